// Round 14
// baseline (55.399 us; speedup 1.0000x reference)
//
#include <hip/hip_runtime.h>
#include <stdint.h>

#define NQ   12
#define DIM  4096   // 2^12 amplitudes
#define TPB  256

typedef float   v2f   __attribute__((ext_vector_type(2)));
typedef float   v4f   __attribute__((ext_vector_type(4)));
typedef float   f32x4 __attribute__((ext_vector_type(4)));
typedef _Float16 v2h  __attribute__((ext_vector_type(2)));
typedef _Float16 f16x8 __attribute__((ext_vector_type(8)));
typedef uint32_t u32x4 __attribute__((ext_vector_type(4)));

// ================= compile-time GF(2) machinery =================
// Layout Λ_P bit->dir: [0]=v0 [1]=v1 [6]=v2 [7]=v3 (read quad + q)
// [8],[9] = T dirs := v0_{P+1}, v1_{P+1} when role-0 & independent (tok)
// [2..5,10,11] = 6 free role-0 dirs. NEW vs r13: when tok, free dirs are
// ALSO filtered ⊥ m0,m1(P+1)  =>  every write-address image into Λ_{P+1}
// has bits 0,1 == 0  =>  b128 stores are aligned and need NO data permute
// (word order == T order, img(T0)=1, img(T1)=2).
// W4 is gated on compile-time-achieved rank-3 over word bits {2,3,4}
// (8 bank-groups, linear-equivalent service); otherwise b32 + rank-5 search.
// Reads stay (n<<2)|(q<<6)|(wv<<10)^(T<<8) exactly (round-10 proven).

constexpr int par(uint32_t x) { return __builtin_popcount(x) & 1; }
constexpr int chbit(uint32_t x) { int b=-1; for (int i=0;i<32;++i) if ((x>>i)&1u) b=i; return b; }

constexpr void bmm(uint32_t* C, const uint32_t* A, const uint32_t* B) {
  for (int i = 0; i < NQ; ++i) {
    uint32_t r = 0;
    for (int j = 0; j < NQ; ++j) if ((A[i] >> j) & 1u) r ^= B[j];
    C[i] = r;
  }
}
constexpr void binv(const uint32_t* M, uint32_t* Inv) {
  uint32_t A[NQ] = {}, I[NQ] = {};
  for (int i = 0; i < NQ; ++i) { A[i] = M[i]; I[i] = 1u << i; }
  for (int c = 0; c < NQ; ++c) {
    int piv = -1;
    for (int r = c; r < NQ; ++r) if ((A[r] >> c) & 1u) { piv = r; break; }
    if (piv < 0) continue;
    uint32_t ta = A[c]; A[c] = A[piv]; A[piv] = ta;
    uint32_t ti = I[c]; I[c] = I[piv]; I[piv] = ti;
    for (int r = 0; r < NQ; ++r)
      if (r != c && ((A[r] >> c) & 1u)) { A[r] ^= A[c]; I[r] ^= I[c]; }
  }
  for (int i = 0; i < NQ; ++i) Inv[i] = I[i];
}

constexpr void pass_vm(int p, uint32_t* v, uint32_t* m) {
  uint32_t A[NQ] = {}; A[0] = 0xFFEu;
  for (int i = 1; i < NQ; ++i) A[i] = (1u << (i + 1)) - 1u;
  uint32_t A2[NQ] = {}, Ai[NQ] = {}, A2i[NQ] = {};
  bmm(A2, A, A); binv(A, Ai); binv(A2, A2i);
  const uint32_t* M  = (p < 3) ? A  : A2;
  const uint32_t* Mi = (p < 3) ? Ai : A2i;
  const int wb = (p % 3) * 4;
  for (int i = 0; i < 4; ++i) {
    uint32_t col = 0;
    for (int r = 0; r < NQ; ++r) col |= ((Mi[r] >> (wb + i)) & 1u) << r;
    v[i] = col; m[i] = M[wb + i];
  }
}

constexpr bool addvec(uint32_t* red, uint32_t x) {
  while (x) {
    const int h = chbit(x);
    if (red[h]) x ^= red[h]; else { red[h] = x; return true; }
  }
  return false;
}
constexpr int rankbits(const uint32_t* w, int n) {
  uint32_t red[8] = {}; int r = 0;
  for (int q = 0; q < n; ++q) {
    uint32_t x = w[q];
    while (x) {
      const int h = chbit(x);
      if (red[h]) x ^= red[h]; else { red[h] = x; ++r; break; }
    }
  }
  return r;
}
constexpr void perm_decode(int idx, int* s) {
  int avail[6] = {0, 1, 2, 3, 4, 5};
  const int f[6] = {120, 24, 6, 2, 1, 1};
  for (int i = 0; i < 6; ++i) {
    const int k = idx / f[i]; idx %= f[i];
    s[i] = avail[k];
    for (int j = k; j < 5 - i; ++j) avail[j] = avail[j + 1];
  }
}

struct Lay { uint32_t d[12]; uint32_t mi[12]; int tok; int lowf; int rank3; };

constexpr Lay make_lay(int p, const Lay& prev, bool hasPrev) {
  Lay L{};
  uint32_t v[4] = {}, m[4] = {};
  pass_vm(p, v, m);
  L.d[0] = v[0]; L.d[1] = v[1]; L.d[6] = v[2]; L.d[7] = v[3];
  uint32_t red[16] = {};
  addvec(red, v[0]); addvec(red, v[1]); addvec(red, v[2]); addvec(red, v[3]);
  L.tok = 0; L.lowf = 0; L.rank3 = 0;
  uint32_t mn0 = 0, mn1 = 0;
  if (p < 5) {
    uint32_t vn[4] = {}, mn[4] = {};
    pass_vm(p + 1, vn, mn);
    mn0 = mn[0]; mn1 = mn[1];
    bool roles0 = true;
    for (int i = 0; i < 4; ++i)
      if (par(m[i] & vn[0]) || par(m[i] & vn[1])) roles0 = false;
    if (roles0) {
      uint32_t tmp[16] = {};
      for (int i = 0; i < 16; ++i) tmp[i] = red[i];
      if (addvec(tmp, vn[0]) && addvec(tmp, vn[1])) {
        addvec(red, vn[0]); addvec(red, vn[1]);
        L.d[8] = vn[0]; L.d[9] = vn[1]; L.tok = 1;
      }
    }
  }
  const int need = L.tok ? 6 : 8;
  uint32_t pool[8] = {}; int np = 0;
  // filtered attempt: free dirs ⊥ m0,m1(P+1) so write images have low bits 0
  if (L.tok) {
    uint32_t red2[16] = {};
    for (int i = 0; i < 16; ++i) red2[i] = red[i];
    uint32_t p2[8] = {}; int n2 = 0;
    for (int b = 0; b < 12 && n2 < need; ++b) {
      uint32_t cand = 1u << b;
      for (int i = 0; i < 4; ++i) if ((m[i] >> b) & 1u) cand ^= v[i];
      if (par(cand & mn0) || par(cand & mn1)) continue;
      if (addvec(red2, cand)) p2[n2++] = cand;
    }
    for (int a = 0; a < 12 && n2 < need; ++a)
      for (int b = a + 1; b < 12 && n2 < need; ++b) {
        uint32_t ca = 1u << a, cb = 1u << b;
        for (int i = 0; i < 4; ++i) {
          if ((m[i] >> a) & 1u) ca ^= v[i];
          if ((m[i] >> b) & 1u) cb ^= v[i];
        }
        uint32_t cand = ca ^ cb;
        if (par(cand & mn0) || par(cand & mn1)) continue;
        if (addvec(red2, cand)) p2[n2++] = cand;
      }
    if (n2 == need) {
      L.lowf = 1;
      for (int i = 0; i < need; ++i) pool[i] = p2[i];
      np = need;
      for (int i = 0; i < 16; ++i) red[i] = red2[i];
    }
  }
  if (np < need) {
    for (int b = 0; b < 12 && np < need; ++b) {
      uint32_t cand = 1u << b;
      for (int i = 0; i < 4; ++i) if ((m[i] >> b) & 1u) cand ^= v[i];
      if (addvec(red, cand)) pool[np++] = cand;
    }
  }
  if (!L.tok) { L.d[8] = pool[6]; L.d[9] = pool[7]; }
  const int S[6] = {2, 3, 4, 5, 10, 11};
  for (int i = 0; i < 6; ++i) L.d[S[i]] = pool[i];   // canonical placement
  uint32_t Mr[NQ] = {}, miC[NQ] = {};
  for (int i = 0; i < NQ; ++i) {
    uint32_t r = 0;
    for (int j = 0; j < NQ; ++j) r |= ((L.d[j] >> i) & 1u) << j;
    Mr[i] = r;
  }
  binv(Mr, miC);
  // incoming-write lane-varying dirs in canonical coords
  uint32_t V[8] = {}; int nv = 0;
  if (!hasPrev) {
    for (int k = 0; k < 8; ++k) {
      uint32_t c = 0;
      for (int bb = 0; bb < 12; ++bb) c |= (uint32_t)par(miC[bb] & (1u << k)) << bb;
      V[nv++] = c;
    }
  } else {
    const uint32_t src[6] = {prev.d[2], prev.d[3], prev.d[4], prev.d[5],
                             prev.d[1], prev.d[6]};
    for (int k = 0; k < 6; ++k) {
      uint32_t c = 0;
      for (int bb = 0; bb < 12; ++bb) c |= (uint32_t)par(miC[bb] & src[k]) << bb;
      V[nv++] = c;
    }
  }
  // does the previous pass want the b128 path into this layout?
  bool wantB128 = false;
  if (hasPrev && prev.tok && prev.lowf) {
    if (!par(m[0] & prev.d[0]) && !par(m[1] & prev.d[0]) &&
        !par(m[0] & prev.d[7]) && !par(m[1] & prev.d[7])) wantB128 = true;
  }
  int bestP = 0, bestSc = -1;
  if (wantB128) {
    for (int pi = 0; pi < 720; ++pi) {
      int sg[6] = {}; perm_decode(pi, sg);
      uint32_t pw[8] = {};
      for (int k = 0; k < nv; ++k) {
        uint32_t w = 0;
        for (int i = 0; i < 3; ++i) w |= (uint32_t)((V[k] >> S[sg[i]]) & 1u) << i;
        pw[k] = w;
      }
      const int sc = rankbits(pw, nv);
      if (sc > bestSc) { bestSc = sc; bestP = pi; }
    }
    if (bestSc >= 3) L.rank3 = 1;
  }
  if (!L.rank3) {        // b32 fallback target: rank-5 over bank bits 0..4
    bestP = 0; bestSc = -1;
    for (int pi = 0; pi < 720; ++pi) {
      int sg[6] = {}; perm_decode(pi, sg);
      uint32_t pw[8] = {};
      for (int k = 0; k < nv; ++k) {
        uint32_t w = V[k] & 3u;
        for (int i = 0; i < 3; ++i) w |= (uint32_t)((V[k] >> S[sg[i]]) & 1u) << (2 + i);
        pw[k] = w;
      }
      const int sc = rankbits(pw, nv);
      if (sc > bestSc) { bestSc = sc; bestP = pi; }
    }
  }
  int sg[6] = {}; perm_decode(bestP, sg);
  for (int i = 0; i < 6; ++i) L.d[S[i]] = pool[sg[i]];
  for (int i = 0; i < NQ; ++i) {
    uint32_t r = 0;
    for (int j = 0; j < NQ; ++j) r |= ((L.d[j] >> i) & 1u) << j;
    Mr[i] = r;
  }
  binv(Mr, L.mi);
  return L;
}

constexpr Lay LY0 = make_lay(0, Lay{}, false);
constexpr Lay LY1 = make_lay(1, LY0, true);
constexpr Lay LY2 = make_lay(2, LY1, true);
constexpr Lay LY3 = make_lay(3, LY2, true);
constexpr Lay LY4 = make_lay(4, LY3, true);
constexpr Lay LY5 = make_lay(5, LY4, true);

constexpr uint32_t imgL(const Lay& l, uint32_t y) {
  uint32_t r = 0;
  for (int b = 0; b < 12; ++b) r |= (uint32_t)par(l.mi[b] & y) << b;
  return r;
}

struct PCon {
  uint32_t WN[4], WQ1, WQ2, WW0, WW1;   // write dirs (images into Λ_{P+1})
  uint32_t WV0, WV3;                     // held-quad dir images
  uint32_t WT0, WT1;                     // T-dir images (==1,2 when tok)
  int      W4;                           // aligned b128 write path
  uint32_t SM[12], robin[12];            // pass-5 readout
  uint8_t  layer, wb;
};

constexpr PCon make_pcon(const Lay& lp, const Lay& ln, int p) {
  PCon c{};
  c.layer = (uint8_t)((p < 3) ? 1 : 2); c.wb = (uint8_t)((p % 3) * 4);
  for (int k = 0; k < 4; ++k) c.WN[k] = imgL(ln, lp.d[2 + k]);
  c.WQ1 = imgL(ln, lp.d[1]);  c.WQ2 = imgL(ln, lp.d[6]);
  c.WW0 = imgL(ln, lp.d[10]); c.WW1 = imgL(ln, lp.d[11]);
  c.WV0 = imgL(ln, lp.d[0]);  c.WV3 = imgL(ln, lp.d[7]);
  c.WT0 = imgL(ln, lp.d[8]);  c.WT1 = imgL(ln, lp.d[9]);
  const bool low = (((c.WN[0] | c.WN[1] | c.WN[2] | c.WN[3] |
                      c.WQ1 | c.WQ2 | c.WW0 | c.WW1 |
                      c.WV0 | c.WV3) & 3u) == 0);
  c.W4 = (lp.tok && c.WT0 == 1u && c.WT1 == 2u && low && ln.rank3) ? 1 : 0;
  return c;
}
constexpr PCon make_pcon5(const Lay& lp) {
  PCon c{};
  c.layer = 2; c.wb = 8; c.W4 = 0;
  uint32_t A[NQ] = {}; A[0] = 0xFFEu;
  for (int i = 1; i < NQ; ++i) A[i] = (1u << (i + 1)) - 1u;
  uint32_t A2[NQ] = {}, A3[NQ] = {};
  bmm(A2, A, A); bmm(A3, A2, A);
  for (int i = 0; i < NQ; ++i) {
    uint32_t sm = 0;
    sm |= (uint32_t)par(A3[i] & lp.d[2])  << 0;
    sm |= (uint32_t)par(A3[i] & lp.d[3])  << 1;
    sm |= (uint32_t)par(A3[i] & lp.d[4])  << 2;
    sm |= (uint32_t)par(A3[i] & lp.d[5])  << 3;
    sm |= (uint32_t)par(A3[i] & lp.d[1])  << 4;
    sm |= (uint32_t)par(A3[i] & lp.d[6])  << 5;
    sm |= (uint32_t)par(A3[i] & lp.d[10]) << 6;
    sm |= (uint32_t)par(A3[i] & lp.d[11]) << 7;
    c.SM[i] = sm;
    c.robin[i] = (uint32_t)par(A3[i] & lp.d[0])
               | (uint32_t)par(A3[i] & lp.d[7]) << 1
               | (uint32_t)par(A3[i] & lp.d[8]) << 2
               | (uint32_t)par(A3[i] & lp.d[9]) << 3;
  }
  return c;
}

constexpr PCon PC0 = make_pcon(LY0, LY1, 0);
constexpr PCon PC1 = make_pcon(LY1, LY2, 1);
constexpr PCon PC2 = make_pcon(LY2, LY3, 2);
constexpr PCon PC3 = make_pcon(LY3, LY4, 3);
constexpr PCon PC4 = make_pcon(LY4, LY5, 4);
constexpr PCon PC5 = make_pcon5(LY5);

template<int P> constexpr PCon pget() {
  if constexpr (P == 0) return PC0;
  else if constexpr (P == 1) return PC1;
  else if constexpr (P == 2) return PC2;
  else if constexpr (P == 3) return PC3;
  else if constexpr (P == 4) return PC4;
  else return PC5;
}

struct InitC { uint32_t ICt[8]; uint32_t ICj[16]; };
constexpr InitC make_init() {
  InitC ic{};
  for (int b = 0; b < 8; ++b) ic.ICt[b] = imgL(LY0, 1u << b);
  uint32_t Jc[4] = {};
  for (int b = 0; b < 4; ++b) Jc[b] = imgL(LY0, 1u << (8 + b));
  for (int j = 0; j < 16; ++j) {
    uint32_t r = 0;
    for (int b = 0; b < 4; ++b) if ((j >> b) & 1) r ^= Jc[b];
    ic.ICj[j] = r;
  }
  return ic;
}
constexpr InitC IC = make_init();

// ================= device helpers =================
__device__ __forceinline__ v2f cmulf(v2f a, v2f b) {
  return (v2f){a.x * b.x - a.y * b.y, a.x * b.y + a.y * b.x};
}
__device__ __forceinline__ uint32_t f2h2(float a, float b) {
  return __builtin_bit_cast(uint32_t, __builtin_amdgcn_cvt_pkrtz(a, b));
}
__device__ __forceinline__ uint32_t pk_rtn(float a, float b) {
  v2h h = {(_Float16)a, (_Float16)b};
  return __builtin_bit_cast(uint32_t, h);
}
__device__ __forceinline__ void build_u(const float* __restrict__ qp, int l, int w, float U[8]) {
  float p0 = qp[(l * 12 + w) * 3 + 0];
  float p1 = qp[(l * 12 + w) * 3 + 1];
  float p2 = qp[(l * 12 + w) * 3 + 2];
  float cx, sx, cy, sy, cz, sz;
  sincosf(0.5f * p0, &sx, &cx);
  sincosf(0.5f * p1, &sy, &cy);
  sincosf(0.5f * p2, &sz, &cz);
  float M00x =  cy * cx, M00y =  sy * sx;
  float M01x = -sy * cx, M01y = -cy * sx;
  float M10x =  sy * cx, M10y = -cy * sx;
  float M11x =  cy * cx, M11y = -sy * sx;
  U[0] = cz * M00x + sz * M00y; U[1] = cz * M00y - sz * M00x;
  U[2] = cz * M01x + sz * M01y; U[3] = cz * M01y - sz * M01x;
  U[4] = cz * M10x - sz * M10y; U[5] = cz * M10y + sz * M10x;
  U[6] = cz * M11x - sz * M11y; U[7] = cz * M11y + sz * M11x;
}
__device__ __forceinline__ int am_col(int c, int i) {
  return ((((c >> 2) ^ ((i >> 1) & 3)) << 2) | (c & 3));
}

template<int P>
__device__ __forceinline__ void build_am_g(uint32_t* __restrict__ Am_g,
                                           const v2f (*gg)[12][4], int t) {
  constexpr PCon pc = pget<P>();
  const int r_ = t >> 4, c_ = t & 15;
  v2f e = (v2f){1.f, 0.f};
  #pragma unroll
  for (int i = 0; i < 4; ++i) {
    v2f u = gg[pc.layer - 1][pc.wb + i][(((r_ >> i) & 1) << 1) | ((c_ >> i) & 1)];
    e = cmulf(e, u);
  }
  const int ra = 2 * r_, rb = 2 * r_ + 1;
  Am_g[P * 512 + ra * 16 + am_col(c_, ra)] = pk_rtn(e.x, -e.y);
  Am_g[P * 512 + rb * 16 + am_col(c_, rb)] = pk_rtn(e.y, e.x);
}

__global__ __launch_bounds__(256) void prep_kernel(const float* __restrict__ qp,
                                                   uint32_t* __restrict__ Am_g,
                                                   float* __restrict__ U0_g) {
  __shared__ v2f gg[2][12][4];
  const int t = threadIdx.x;
  if (t < 24) {
    const int L = t / 12 + 1, w = t % 12;
    float U[8]; build_u(qp, L, w, U);
    gg[L - 1][w][0] = (v2f){U[0], U[1]};
    gg[L - 1][w][1] = (v2f){U[2], U[3]};
    gg[L - 1][w][2] = (v2f){U[4], U[5]};
    gg[L - 1][w][3] = (v2f){U[6], U[7]};
  } else if (t >= 32 && t < 44) {
    const int w = t - 32;
    float U[8]; build_u(qp, 0, w, U);
    #pragma unroll
    for (int k = 0; k < 8; ++k) U0_g[w * 8 + k] = U[k];
  }
  __syncthreads();
  build_am_g<0>(Am_g, gg, t);
  build_am_g<1>(Am_g, gg, t);
  build_am_g<2>(Am_g, gg, t);
  build_am_g<3>(Am_g, gg, t);
  build_am_g<4>(Am_g, gg, t);
  build_am_g<5>(Am_g, gg, t);
}

// ================= per-pass MFMA engine =================
template<int P, bool LAST>
__device__ __forceinline__ void do_pass(uint32_t* st, f16x8 a0, f16x8 a1,
                                        int lane, int wvl, float* ev) {
  constexpr PCon pc = pget<P>();
  const int n = lane & 15, q = lane >> 4;
  const int rb = (n << 2) | (q << 6) | (wvl << 10);   // trivial read base (round-10)
  int wb_ = 0;
  if constexpr (!LAST) {
    wb_ = ((n & 1) ? pc.WN[0] : 0) ^ ((n & 2) ? pc.WN[1] : 0)
        ^ ((n & 4) ? pc.WN[2] : 0) ^ ((n & 8) ? pc.WN[3] : 0)
        ^ ((q & 1) ? pc.WQ1 : 0)   ^ ((q & 2) ? pc.WQ2 : 0)
        ^ ((wvl & 1) ? pc.WW0 : 0) ^ ((wvl & 2) ? pc.WW1 : 0);
  }
  const f32x4 z = {0.f, 0.f, 0.f, 0.f};
  if constexpr (!LAST && pc.W4) {
    uint32_t wbuf[4][4];   // [quad-combo c][T]; word order == T order (img T = 1,2)
    #pragma unroll
    for (int T = 0; T < 4; ++T) {
      u32x4 braw = *reinterpret_cast<const u32x4*>(&st[rb ^ (T << 8)]);
      f16x8 bf = __builtin_bit_cast(f16x8, braw);
      f32x4 c0 = __builtin_amdgcn_mfma_f32_16x16x32_f16(a0, bf, z, 0, 0, 0);
      f32x4 c1 = __builtin_amdgcn_mfma_f32_16x16x32_f16(a1, bf, z, 0, 0, 0);
      wbuf[0][T] = f2h2(c0.x, c0.y);
      wbuf[1][T] = f2h2(c0.z, c0.w);
      wbuf[2][T] = f2h2(c1.x, c1.y);
      wbuf[3][T] = f2h2(c1.z, c1.w);
    }
    #pragma unroll
    for (int c = 0; c < 4; ++c) {
      const int A = wb_ ^ ((c & 1) ? pc.WV0 : 0) ^ ((c & 2) ? pc.WV3 : 0);
      // all write dirs have bits 0,1 == 0 by construction: aligned, no permute
      *reinterpret_cast<u32x4*>(&st[A]) =
          (u32x4){wbuf[c][0], wbuf[c][1], wbuf[c][2], wbuf[c][3]};
    }
  } else if constexpr (!LAST) {
    #pragma unroll
    for (int T = 0; T < 4; ++T) {
      u32x4 braw = *reinterpret_cast<const u32x4*>(&st[rb ^ (T << 8)]);
      f16x8 bf = __builtin_bit_cast(f16x8, braw);
      f32x4 c0 = __builtin_amdgcn_mfma_f32_16x16x32_f16(a0, bf, z, 0, 0, 0);
      f32x4 c1 = __builtin_amdgcn_mfma_f32_16x16x32_f16(a1, bf, z, 0, 0, 0);
      const int A = wb_ ^ ((T & 1) ? pc.WT0 : 0) ^ ((T & 2) ? pc.WT1 : 0);
      st[A]                      = f2h2(c0.x, c0.y);
      st[A ^ pc.WV0]             = f2h2(c0.z, c0.w);
      st[A ^ pc.WV3]             = f2h2(c1.x, c1.y);
      st[A ^ (pc.WV0 ^ pc.WV3)]  = f2h2(c1.z, c1.w);
    }
  } else {
    float pr[16];
    #pragma unroll
    for (int T = 0; T < 4; ++T) {
      u32x4 braw = *reinterpret_cast<const u32x4*>(&st[rb ^ (T << 8)]);
      f16x8 bf = __builtin_bit_cast(f16x8, braw);
      f32x4 c0 = __builtin_amdgcn_mfma_f32_16x16x32_f16(a0, bf, z, 0, 0, 0);
      f32x4 c1 = __builtin_amdgcn_mfma_f32_16x16x32_f16(a1, bf, z, 0, 0, 0);
      const int nb = ((T & 1) << 2) | ((T >> 1) << 3);
      pr[nb]     = c0.x * c0.x + c0.y * c0.y;
      pr[nb | 1] = c0.z * c0.z + c0.w * c0.w;
      pr[nb | 2] = c1.x * c1.x + c1.y * c1.y;
      pr[nb | 3] = c1.z * c1.z + c1.w * c1.w;
    }
    #pragma unroll
    for (int gs = 1; gs < 16; gs <<= 1) {
      #pragma unroll
      for (int j = 0; j < 16; ++j) {
        if (j & gs) continue;
        float u = pr[j], w2 = pr[j | gs];
        pr[j] = u + w2; pr[j | gs] = u - w2;
      }
    }
    const int pw = n | (q << 4) | (wvl << 6);
    #pragma unroll
    for (int i = 0; i < NQ; ++i) {
      float h = pr[pc.robin[i]];
      int s = (__popc((int)pc.SM[i] & pw) & 1) << 31;
      ev[i] = __int_as_float(__float_as_int(h) ^ s);
    }
  }
}

// A-fragment global load (L2-hot 12KB table), one pass ahead of use
#define LDA(P, A0, A1) {                                                        \
  const int li_ = lane & 15;                                                    \
  const int q_  = (lane >> 4) ^ ((li_ >> 1) & 3);                               \
  A0 = __builtin_bit_cast(f16x8,                                                \
      *reinterpret_cast<const u32x4*>(Am_g + (P) * 512 + li_ * 16 + q_ * 4));   \
  A1 = __builtin_bit_cast(f16x8,                                                \
      *reinterpret_cast<const u32x4*>(Am_g + (P) * 512 + (li_ + 16) * 16 + q_ * 4)); \
}

// ================= main kernel =================
__global__ __launch_bounds__(TPB, 8) void hqc_kernel(
    const float* __restrict__ x,  const float* __restrict__ W1, const float* __restrict__ b1,
    const float* __restrict__ W2, const float* __restrict__ b2,
    const float* __restrict__ W3, const float* __restrict__ b3,
    const float* __restrict__ P1, const float* __restrict__ c1,
    const float* __restrict__ P2, const float* __restrict__ c2,
    const float* __restrict__ P3, const float* __restrict__ c3,
    const uint32_t* __restrict__ Am_g, const float* __restrict__ U0_g,
    float* __restrict__ out)
{
  __shared__ __align__(16) uint32_t st[DIM];   // 16 KB packed-half2 state
  __shared__ v4f  gpk0[12][2];
  __shared__ float red[4][NQ];

  const int s    = blockIdx.x;
  const int t    = threadIdx.x;
  const int lane = t & 63;
  const int wv   = t >> 6;

  f16x8 a0c, a1c, a0n, a1n;
  LDA(0, a0c, a1c)

  // ---- wave0: MLP + L0 fold; one barrier ----
  if (wv == 0 && lane < 16) {
    float a = b1[lane];
    #pragma unroll
    for (int k = 0; k < 6; ++k) a = fmaf(W1[lane * 6 + k], x[s * 6 + k], a);
    float h1 = fmaxf(a, 0.f);
    float a2 = b2[lane];
    #pragma unroll
    for (int k = 0; k < 16; ++k) a2 = fmaf(W2[lane * 16 + k], __shfl(h1, k, 64), a2);
    float h2 = fmaxf(a2, 0.f);
    const int lw = (lane < NQ) ? lane : 0;
    float a3 = b3[lw];
    #pragma unroll
    for (int k = 0; k < 16; ++k) a3 = fmaf(W3[lw * 16 + k], __shfl(h2, k, 64), a3);
    if (lane < NQ) {
      const float* u = U0_g + lane * 8;
      float ca, sa; sincosf(0.5f * a3, &sa, &ca);
      float c0x = u[0] * ca + u[2] * sa, c0y = u[1] * ca + u[3] * sa;
      float c1x = u[4] * ca + u[6] * sa, c1y = u[5] * ca + u[7] * sa;
      gpk0[lane][0] = (v4f){c0x, c0x, -c0y, c0y};
      gpk0[lane][1] = (v4f){c1x, c1x, -c1y, c1y};
    }
  }
  __syncthreads();

  // ---- product-state init, written directly in Λ_0 layout ----
  {
    int tb = 0;
    #pragma unroll
    for (int b = 0; b < 8; ++b) if ((t >> b) & 1) tb ^= IC.ICt[b];
    v2f acc = (v2f){1.f, 0.f};
    #pragma unroll
    for (int i = 0; i < 8; ++i) {
      v4f gk = gpk0[i][(t >> i) & 1];
      acc = gk.xy * acc + gk.zw * acc.yx;
    }
    v2f l16[16];
    l16[0] = acc;
    #pragma unroll
    for (int i = 0; i < 4; ++i) {
      v4f g0 = gpk0[8 + i][0], g1 = gpk0[8 + i][1];
      #pragma unroll
      for (int j = 0; j < (1 << i); ++j) {
        v2f a = l16[j];
        l16[j | (1 << i)] = g1.xy * a + g1.zw * a.yx;
        l16[j]            = g0.xy * a + g0.zw * a.yx;
      }
    }
    #pragma unroll
    for (int j = 0; j < 16; ++j) st[tb ^ IC.ICj[j]] = f2h2(l16[j].x, l16[j].y);
  }
  __syncthreads();

  float ev[NQ];
  LDA(1, a0n, a1n)
  do_pass<0, false>(st, a0c, a1c, lane, wv, ev); __syncthreads();
  a0c = a0n; a1c = a1n; LDA(2, a0n, a1n)
  do_pass<1, false>(st, a0c, a1c, lane, wv, ev); __syncthreads();
  a0c = a0n; a1c = a1n; LDA(3, a0n, a1n)
  do_pass<2, false>(st, a0c, a1c, lane, wv, ev); __syncthreads();
  a0c = a0n; a1c = a1n; LDA(4, a0n, a1n)
  do_pass<3, false>(st, a0c, a1c, lane, wv, ev); __syncthreads();
  a0c = a0n; a1c = a1n; LDA(5, a0n, a1n)
  do_pass<4, false>(st, a0c, a1c, lane, wv, ev); __syncthreads();
  a0c = a0n; a1c = a1n;
  do_pass<5, true >(st, a0c, a1c, lane, wv, ev);  // fused readout

  // ---- reduce across lanes, then waves ----
  #pragma unroll
  for (int off = 32; off >= 1; off >>= 1) {
    #pragma unroll
    for (int i = 0; i < NQ; ++i) ev[i] += __shfl_xor(ev[i], off, 64);
  }
  if (lane == 0) {
    #pragma unroll
    for (int i = 0; i < NQ; ++i) red[wv][i] = ev[i];
  }
  __syncthreads();

  // ---- post-MLP on wave 0 via shuffles ----
  if (wv == 0 && lane < 16) {
    float q = (lane < NQ)
      ? (red[0][lane] + red[1][lane] + red[2][lane] + red[3][lane])
      : 0.f;
    float a = c1[lane];
    #pragma unroll
    for (int j = 0; j < NQ; ++j) a = fmaf(P1[lane * NQ + j], __shfl(q, j, 64), a);
    float o1 = fmaxf(a, 0.f);
    float a2 = c2[lane & 7];
    #pragma unroll
    for (int j = 0; j < 16; ++j) a2 = fmaf(P2[(lane & 7) * 16 + j], __shfl(o1, j, 64), a2);
    float o2 = fmaxf(a2, 0.f);
    float a3 = c3[0];
    #pragma unroll
    for (int j = 0; j < 8; ++j) a3 = fmaf(P3[j], __shfl(o2, j, 64), a3);
    if (lane == 0) out[s] = 1.f / (1.f + expf(-a3));
  }
}

extern "C" void kernel_launch(void* const* d_in, const int* in_sizes, int n_in,
                              void* d_out, int out_size, void* d_ws, size_t ws_size,
                              hipStream_t stream) {
  (void)in_sizes; (void)n_in; (void)ws_size;
  uint32_t* Am_g = (uint32_t*)d_ws;                       // 6*512*4 = 12288 B
  float*    U0_g = (float*)((char*)d_ws + 6 * 512 * 4);   // 12*8*4  =   384 B
  const float* qp = (const float*)d_in[7];
  prep_kernel<<<1, 256, 0, stream>>>(qp, Am_g, U0_g);
  hqc_kernel<<<out_size, TPB, 0, stream>>>(
      (const float*)d_in[0],  (const float*)d_in[1],  (const float*)d_in[2],
      (const float*)d_in[3],  (const float*)d_in[4],  (const float*)d_in[5],
      (const float*)d_in[6],
      (const float*)d_in[8],  (const float*)d_in[9],
      (const float*)d_in[10], (const float*)d_in[11],
      (const float*)d_in[12], (const float*)d_in[13],
      Am_g, U0_g,
      (float*)d_out);
}

// Round 15
// 48.149 us; speedup vs baseline: 1.1506x; 1.1506x over previous
//
#include <hip/hip_runtime.h>
#include <stdint.h>

#define NQ   12
#define DIM  4096   // 2^12 amplitudes
#define TPB  256

typedef float   v2f   __attribute__((ext_vector_type(2)));
typedef float   v4f   __attribute__((ext_vector_type(4)));
typedef float   f32x4 __attribute__((ext_vector_type(4)));
typedef _Float16 v2h  __attribute__((ext_vector_type(2)));
typedef _Float16 f16x8 __attribute__((ext_vector_type(8)));
typedef uint32_t u32x4 __attribute__((ext_vector_type(4)));

// ---------- compile-time GF(2) machinery (round-10 proven optimum) ----------
struct PassL {
  uint32_t v[4], m[4];
  uint32_t Be[8];
  uint8_t  np[8];
  uint8_t  layer, wb;
};
struct PassC {
  uint16_t WD[8];
  uint16_t WQ1, WQ2;
  uint16_t WV0, WV3;
  uint16_t SM[12];
  uint8_t  robin[12];
  uint8_t  layer, wb;
};
struct InitC { uint16_t ICt[8]; uint16_t ICj[16]; };

constexpr int par(uint32_t x) { return __builtin_popcount(x) & 1; }

constexpr void bmm(uint32_t* C, const uint32_t* A, const uint32_t* B) {
  for (int i = 0; i < NQ; ++i) {
    uint32_t r = 0;
    for (int j = 0; j < NQ; ++j) if ((A[i] >> j) & 1u) r ^= B[j];
    C[i] = r;
  }
}
constexpr void binv(const uint32_t* M, uint32_t* Inv) {
  uint32_t A[NQ] = {}, I[NQ] = {};
  for (int i = 0; i < NQ; ++i) { A[i] = M[i]; I[i] = 1u << i; }
  for (int c = 0; c < NQ; ++c) {
    int piv = -1;
    for (int r = c; r < NQ; ++r) if ((A[r] >> c) & 1u) { piv = r; break; }
    if (piv < 0) continue;
    uint32_t ta = A[c]; A[c] = A[piv]; A[piv] = ta;
    uint32_t ti = I[c]; I[c] = I[piv]; I[piv] = ti;
    for (int r = 0; r < NQ; ++r)
      if (r != c && ((A[r] >> c) & 1u)) { A[r] ^= A[c]; I[r] ^= I[c]; }
  }
  for (int i = 0; i < NQ; ++i) Inv[i] = I[i];
}
constexpr int rank5(const uint32_t* cols, int n) {
  uint32_t rows[5] = {}; int rnk = 0;
  for (int q = 0; q < n; ++q) {
    uint32_t x = cols[q] & 31u;
    for (int bit = 4; bit >= 0; --bit) {
      if (!((x >> bit) & 1u)) continue;
      if (rows[bit]) { x ^= rows[bit]; }
      else { rows[bit] = x; ++rnk; break; }
    }
  }
  return rnk;
}

constexpr PassL passL_default(int p) {
  PassL L{};
  uint32_t A[NQ] = {}; A[0] = 0xFFEu;
  for (int i = 1; i < NQ; ++i) A[i] = (1u << (i + 1)) - 1u;
  uint32_t A2[NQ] = {}, Ai[NQ] = {}, A2i[NQ] = {};
  bmm(A2, A, A); binv(A, Ai); binv(A2, A2i);
  const int Lr = (p < 3) ? 1 : 2, wb = (p % 3) * 4;
  const uint32_t* M  = (Lr == 1) ? A  : A2;
  const uint32_t* Mi = (Lr == 1) ? Ai : A2i;
  for (int i = 0; i < 4; ++i) {
    const int w = wb + i; uint32_t col = 0;
    for (int r = 0; r < NQ; ++r) col |= ((Mi[r] >> w) & 1u) << r;
    L.v[i] = col; L.m[i] = M[w];
  }
  uint32_t Bc[NQ] = {};
  for (int b = 0; b < NQ; ++b) {
    uint32_t col = 1u << b;
    for (int i = 0; i < 4; ++i) if ((L.m[i] >> b) & 1u) col ^= L.v[i];
    Bc[b] = col;
  }
  uint32_t redv[4] = {}; uint32_t pivmask = 0;
  for (int i = 0; i < 4; ++i) {
    redv[i] = L.v[i];
    for (int k = 0; k < i; ++k) {
      int pb = 0;
      for (int b = 0; b < NQ; ++b) if ((redv[k] >> b) & 1u) pb = b;
      if ((redv[i] >> pb) & 1u) redv[i] ^= redv[k];
    }
    int pb = 0;
    for (int b = 0; b < NQ; ++b) if ((redv[i] >> b) & 1u) pb = b;
    pivmask |= 1u << pb;
  }
  int c = 0;
  for (int b = 0; b < NQ; ++b)
    if (!((pivmask >> b) & 1u)) { L.np[c] = (uint8_t)b; L.Be[c] = Bc[b]; ++c; }
  L.layer = (uint8_t)Lr; L.wb = (uint8_t)wb;
  return L;
}

constexpr uint8_t ASSIGN[12] = {0, 1, 6, 7, 2, 3, 4, 5, 8, 9, 10, 11};
struct Lam { uint32_t minv[NQ]; };
constexpr Lam make_lam(const PassL& L) {
  uint32_t bas[12] = {L.v[0], L.v[1], L.v[2], L.v[3],
                      L.Be[0], L.Be[1], L.Be[2], L.Be[3],
                      L.Be[4], L.Be[5], L.Be[6], L.Be[7]};
  uint32_t Mr[NQ] = {};
  for (int i = 0; i < NQ; ++i) {
    uint32_t r = 0;
    for (int j = 0; j < NQ; ++j) r |= ((bas[j] >> i) & 1u) << j;
    Mr[i] = r;
  }
  Lam lm{};
  binv(Mr, lm.minv);
  return lm;
}
constexpr uint32_t lap(const Lam& lm, uint32_t y) {
  uint32_t r = 0;
  for (int j = 0; j < NQ; ++j)
    if (par(lm.minv[j] & y)) r ^= 1u << ASSIGN[j];
  return r;
}

constexpr int P4[24][4] = {
  {0,1,2,3},{0,1,3,2},{0,2,1,3},{0,2,3,1},{0,3,1,2},{0,3,2,1},
  {1,0,2,3},{1,0,3,2},{1,2,0,3},{1,2,3,0},{1,3,0,2},{1,3,2,0},
  {2,0,1,3},{2,0,3,1},{2,1,0,3},{2,1,3,0},{2,3,0,1},{2,3,1,0},
  {3,0,1,2},{3,0,2,1},{3,1,0,2},{3,1,2,0},{3,2,0,1},{3,2,1,0}};

constexpr PassL reorder_np(const PassL& L, int pi, int s45, int s67) {
  PassL T = L;
  for (int k = 0; k < 4; ++k) { T.np[k] = L.np[P4[pi][k]]; T.Be[k] = L.Be[P4[pi][k]]; }
  if (s45) { T.np[4] = L.np[5]; T.np[5] = L.np[4]; T.Be[4] = L.Be[5]; T.Be[5] = L.Be[4]; }
  if (s67) { T.np[6] = L.np[7]; T.np[7] = L.np[6]; T.Be[6] = L.Be[7]; T.Be[7] = L.Be[6]; }
  return T;
}

constexpr PassL passL_ordered(int p, const PassL& prev) {
  const PassL L = passL_default(p);
  int best = -1; PassL bestL = L;
  for (int pi = 0; pi < 24; ++pi)
  for (int s45 = 0; s45 < 2; ++s45)
  for (int s67 = 0; s67 < 2; ++s67) {
    const PassL T = reorder_np(L, pi, s45, s67);
    const Lam lm = make_lam(T);
    uint32_t g[8] = { lap(lm, prev.Be[0]), lap(lm, prev.Be[1]),
                      lap(lm, prev.Be[2]), lap(lm, prev.Be[3]),
                      lap(lm, prev.v[1]),  lap(lm, prev.v[2]),
                      lap(lm, prev.Be[6]), lap(lm, prev.Be[7]) };
    const int r = rank5(g, 8);
    if (r > best) { best = r; bestL = T; }
  }
  return bestL;
}

constexpr PassL L0 = passL_default(0);
constexpr PassL L1 = passL_ordered(1, L0);
constexpr PassL L2 = passL_ordered(2, L1);
constexpr PassL L3 = passL_ordered(3, L2);
constexpr PassL L4 = passL_ordered(4, L3);
constexpr PassL L5 = passL_ordered(5, L4);

constexpr PassC make_passC(const PassL& L, const PassL& Ln) {
  PassC c{};
  const Lam lm = make_lam(Ln);
  for (int k = 0; k < 8; ++k) c.WD[k] = (uint16_t)lap(lm, L.Be[k]);
  c.WQ1 = (uint16_t)lap(lm, L.v[1]); c.WQ2 = (uint16_t)lap(lm, L.v[2]);
  c.WV0 = (uint16_t)lap(lm, L.v[0]); c.WV3 = (uint16_t)lap(lm, L.v[3]);
  c.layer = L.layer; c.wb = L.wb;
  return c;
}
constexpr PassC make_passC5(const PassL& L) {
  PassC c{};
  uint32_t A[NQ] = {}; A[0] = 0xFFEu;
  for (int i = 1; i < NQ; ++i) A[i] = (1u << (i + 1)) - 1u;
  uint32_t A2[NQ] = {}, A3[NQ] = {};
  bmm(A2, A, A); bmm(A3, A2, A);
  for (int i = 0; i < NQ; ++i) {
    uint32_t sm = 0;
    sm |= (uint32_t)par(A3[i] & L.Be[0]) << 0;
    sm |= (uint32_t)par(A3[i] & L.Be[1]) << 1;
    sm |= (uint32_t)par(A3[i] & L.Be[2]) << 2;
    sm |= (uint32_t)par(A3[i] & L.Be[3]) << 3;
    sm |= (uint32_t)par(A3[i] & L.v[1])  << 4;
    sm |= (uint32_t)par(A3[i] & L.v[2])  << 5;
    sm |= (uint32_t)par(A3[i] & L.Be[6]) << 6;
    sm |= (uint32_t)par(A3[i] & L.Be[7]) << 7;
    c.SM[i] = (uint16_t)sm;
    uint32_t b = (uint32_t)par(A3[i] & L.v[0])
               | (uint32_t)par(A3[i] & L.v[3])  << 1
               | (uint32_t)par(A3[i] & L.Be[4]) << 2
               | (uint32_t)par(A3[i] & L.Be[5]) << 3;
    c.robin[i] = (uint8_t)b;
  }
  c.layer = L.layer; c.wb = L.wb;
  return c;
}
constexpr InitC make_init(const PassL& L) {
  InitC ic{};
  const Lam lm = make_lam(L);
  for (int b = 0; b < 8; ++b) ic.ICt[b] = (uint16_t)lap(lm, 1u << b);
  uint32_t Jc[4] = {};
  for (int b = 0; b < 4; ++b) Jc[b] = lap(lm, 1u << (8 + b));
  for (int j = 0; j < 16; ++j) {
    uint32_t r = 0;
    for (int b = 0; b < 4; ++b) if ((j >> b) & 1) r ^= Jc[b];
    ic.ICj[j] = (uint16_t)r;
  }
  return ic;
}

constexpr PassC C0 = make_passC(L0, L1);
constexpr PassC C1 = make_passC(L1, L2);
constexpr PassC C2 = make_passC(L2, L3);
constexpr PassC C3 = make_passC(L3, L4);
constexpr PassC C4 = make_passC(L4, L5);
constexpr PassC C5 = make_passC5(L5);
constexpr InitC IC = make_init(L0);

template<int P> constexpr PassC cget() {
  if constexpr (P == 0) return C0;
  else if constexpr (P == 1) return C1;
  else if constexpr (P == 2) return C2;
  else if constexpr (P == 3) return C3;
  else if constexpr (P == 4) return C4;
  else return C5;
}

// ---------- device helpers ----------
__device__ __forceinline__ v2f cmulf(v2f a, v2f b) {
  return (v2f){a.x * b.x - a.y * b.y, a.x * b.y + a.y * b.x};
}
__device__ __forceinline__ uint32_t f2h2(float a, float b) {
  return __builtin_bit_cast(uint32_t, __builtin_amdgcn_cvt_pkrtz(a, b));
}
__device__ __forceinline__ uint32_t pk_rtn(float a, float b) {
  v2h h = {(_Float16)a, (_Float16)b};
  return __builtin_bit_cast(uint32_t, h);
}
__device__ __forceinline__ void build_u(const float* __restrict__ qp, int l, int w, float U[8]) {
  float p0 = qp[(l * 12 + w) * 3 + 0];
  float p1 = qp[(l * 12 + w) * 3 + 1];
  float p2 = qp[(l * 12 + w) * 3 + 2];
  float cx, sx, cy, sy, cz, sz;
  sincosf(0.5f * p0, &sx, &cx);
  sincosf(0.5f * p1, &sy, &cy);
  sincosf(0.5f * p2, &sz, &cz);
  float M00x =  cy * cx, M00y =  sy * sx;
  float M01x = -sy * cx, M01y = -cy * sx;
  float M10x =  sy * cx, M10y = -cy * sx;
  float M11x =  cy * cx, M11y = -sy * sx;
  U[0] = cz * M00x + sz * M00y; U[1] = cz * M00y - sz * M00x;
  U[2] = cz * M01x + sz * M01y; U[3] = cz * M01y - sz * M01x;
  U[4] = cz * M10x - sz * M10y; U[5] = cz * M10y + sz * M10x;
  U[6] = cz * M11x - sz * M11y; U[7] = cz * M11y + sz * M11x;
}
__device__ __forceinline__ int am_col(int c, int i) {
  return ((((c >> 2) ^ ((i >> 1) & 3)) << 2) | (c & 3));
}

template<int P>
__device__ __forceinline__ void build_am_g(uint32_t* __restrict__ Am_g,
                                           const v2f (*gg)[12][4], int t) {
  constexpr PassC pc = cget<P>();
  const int r_ = t >> 4, c_ = t & 15;
  v2f e = (v2f){1.f, 0.f};
  #pragma unroll
  for (int i = 0; i < 4; ++i) {
    v2f u = gg[pc.layer - 1][pc.wb + i][(((r_ >> i) & 1) << 1) | ((c_ >> i) & 1)];
    e = cmulf(e, u);
  }
  const int ra = 2 * r_, rb = 2 * r_ + 1;
  Am_g[P * 512 + ra * 16 + am_col(c_, ra)] = pk_rtn(e.x, -e.y);
  Am_g[P * 512 + rb * 16 + am_col(c_, rb)] = pk_rtn(e.y, e.x);
}

__global__ __launch_bounds__(256) void prep_kernel(const float* __restrict__ qp,
                                                   uint32_t* __restrict__ Am_g,
                                                   float* __restrict__ U0_g) {
  __shared__ v2f gg[2][12][4];
  const int t = threadIdx.x;
  if (t < 24) {
    const int L = t / 12 + 1, w = t % 12;
    float U[8]; build_u(qp, L, w, U);
    gg[L - 1][w][0] = (v2f){U[0], U[1]};
    gg[L - 1][w][1] = (v2f){U[2], U[3]};
    gg[L - 1][w][2] = (v2f){U[4], U[5]};
    gg[L - 1][w][3] = (v2f){U[6], U[7]};
  } else if (t >= 32 && t < 44) {
    const int w = t - 32;
    float U[8]; build_u(qp, 0, w, U);
    #pragma unroll
    for (int k = 0; k < 8; ++k) U0_g[w * 8 + k] = U[k];
  }
  __syncthreads();
  build_am_g<0>(Am_g, gg, t);
  build_am_g<1>(Am_g, gg, t);
  build_am_g<2>(Am_g, gg, t);
  build_am_g<3>(Am_g, gg, t);
  build_am_g<4>(Am_g, gg, t);
  build_am_g<5>(Am_g, gg, t);
}

// ---------- per-pass MFMA engine: b128 reads, rank-optimal b32 writes ----------
// s_setprio(1) wraps the MFMA/LDS body (T5): blocks on a CU are de-phased and
// independent, so priority keeps MFMA-ready waves fed (attn-style, m191).
template<int P, bool LAST>
__device__ __forceinline__ void do_pass(uint32_t* st, f16x8 a0, f16x8 a1,
                                        int lane, int wvl, float* ev) {
  constexpr PassC pc = cget<P>();
  const int n = lane & 15, q = lane >> 4;
  const int rb = (n << 2) | (q << 6) | (wvl << 10);   // trivial read base
  int wb_ = 0;
  if constexpr (!LAST) {
    wb_ = ((n & 1) ? pc.WD[0] : 0) ^ ((n & 2) ? pc.WD[1] : 0)
        ^ ((n & 4) ? pc.WD[2] : 0) ^ ((n & 8) ? pc.WD[3] : 0)
        ^ ((q & 1) ? pc.WQ1 : 0)   ^ ((q & 2) ? pc.WQ2 : 0)
        ^ ((wvl & 1) ? pc.WD[6] : 0) ^ ((wvl & 2) ? pc.WD[7] : 0);
  }
  float pr[16];
  const f32x4 z = {0.f, 0.f, 0.f, 0.f};
  __builtin_amdgcn_s_setprio(1);
  #pragma unroll
  for (int T = 0; T < 4; ++T) {
    u32x4 braw = *reinterpret_cast<const u32x4*>(&st[rb + (T << 8)]);  // ds_read_b128
    f16x8 bf = __builtin_bit_cast(f16x8, braw);
    f32x4 c0 = __builtin_amdgcn_mfma_f32_16x16x32_f16(a0, bf, z, 0, 0, 0);
    f32x4 c1 = __builtin_amdgcn_mfma_f32_16x16x32_f16(a1, bf, z, 0, 0, 0);
    if constexpr (!LAST) {
      const int wa = wb_ ^ ((T & 1) ? pc.WD[4] : 0) ^ ((T & 2) ? pc.WD[5] : 0);
      st[wa]                       = f2h2(c0.x, c0.y);
      st[wa ^ pc.WV0]              = f2h2(c0.z, c0.w);
      st[wa ^ pc.WV3]              = f2h2(c1.x, c1.y);
      st[wa ^ (pc.WV0 ^ pc.WV3)]   = f2h2(c1.z, c1.w);
    } else {
      const int nb = ((T & 1) << 2) | ((T >> 1) << 3);
      pr[nb]     = c0.x * c0.x + c0.y * c0.y;
      pr[nb | 1] = c0.z * c0.z + c0.w * c0.w;
      pr[nb | 2] = c1.x * c1.x + c1.y * c1.y;
      pr[nb | 3] = c1.z * c1.z + c1.w * c1.w;
    }
  }
  __builtin_amdgcn_s_setprio(0);
  if constexpr (LAST) {
    #pragma unroll
    for (int gs = 1; gs < 16; gs <<= 1) {
      #pragma unroll
      for (int j = 0; j < 16; ++j) {
        if (j & gs) continue;
        float u = pr[j], w2 = pr[j | gs];
        pr[j] = u + w2; pr[j | gs] = u - w2;
      }
    }
    const int pw = n | (q << 4) | (wvl << 6);
    #pragma unroll
    for (int i = 0; i < NQ; ++i) {
      float h = pr[pc.robin[i]];
      int s = (__popc(pc.SM[i] & pw) & 1) << 31;
      ev[i] = __int_as_float(__float_as_int(h) ^ s);
    }
  }
}

// A-fragment global load (L2-hot 12KB table), one pass ahead of use
#define LDA(P, A0, A1) {                                                        \
  const int li_ = lane & 15;                                                    \
  const int q_  = (lane >> 4) ^ ((li_ >> 1) & 3);                               \
  A0 = __builtin_bit_cast(f16x8,                                                \
      *reinterpret_cast<const u32x4*>(Am_g + (P) * 512 + li_ * 16 + q_ * 4));   \
  A1 = __builtin_bit_cast(f16x8,                                                \
      *reinterpret_cast<const u32x4*>(Am_g + (P) * 512 + (li_ + 16) * 16 + q_ * 4)); \
}

// ---------- main kernel ----------
__global__ __launch_bounds__(TPB, 8) void hqc_kernel(
    const float* __restrict__ x,  const float* __restrict__ W1, const float* __restrict__ b1,
    const float* __restrict__ W2, const float* __restrict__ b2,
    const float* __restrict__ W3, const float* __restrict__ b3,
    const float* __restrict__ P1, const float* __restrict__ c1,
    const float* __restrict__ P2, const float* __restrict__ c2,
    const float* __restrict__ P3, const float* __restrict__ c3,
    const uint32_t* __restrict__ Am_g, const float* __restrict__ U0_g,
    float* __restrict__ out)
{
  __shared__ __align__(16) uint32_t st[DIM];   // 16 KB packed-half2 state
  __shared__ v4f  gpk0[12][2];
  __shared__ float red[4][NQ];

  const int s    = blockIdx.x;
  const int t    = threadIdx.x;
  const int lane = t & 63;
  const int wv   = t >> 6;

  f16x8 a0c, a1c, a0n, a1n;
  LDA(0, a0c, a1c)

  // ---- wave0: MLP + L0 fold; one barrier ----
  if (wv == 0 && lane < 16) {
    float a = b1[lane];
    #pragma unroll
    for (int k = 0; k < 6; ++k) a = fmaf(W1[lane * 6 + k], x[s * 6 + k], a);
    float h1 = fmaxf(a, 0.f);
    float a2 = b2[lane];
    #pragma unroll
    for (int k = 0; k < 16; ++k) a2 = fmaf(W2[lane * 16 + k], __shfl(h1, k, 64), a2);
    float h2 = fmaxf(a2, 0.f);
    const int lw = (lane < NQ) ? lane : 0;
    float a3 = b3[lw];
    #pragma unroll
    for (int k = 0; k < 16; ++k) a3 = fmaf(W3[lw * 16 + k], __shfl(h2, k, 64), a3);
    if (lane < NQ) {
      const float* u = U0_g + lane * 8;
      float ca, sa; sincosf(0.5f * a3, &sa, &ca);
      float c0x = u[0] * ca + u[2] * sa, c0y = u[1] * ca + u[3] * sa;
      float c1x = u[4] * ca + u[6] * sa, c1y = u[5] * ca + u[7] * sa;
      gpk0[lane][0] = (v4f){c0x, c0x, -c0y, c0y};
      gpk0[lane][1] = (v4f){c1x, c1x, -c1y, c1y};
    }
  }
  __syncthreads();

  // ---- product-state init, written directly in Lambda_0 layout ----
  {
    int tb = 0;
    #pragma unroll
    for (int b = 0; b < 8; ++b) if ((t >> b) & 1) tb ^= IC.ICt[b];
    v2f acc = (v2f){1.f, 0.f};
    #pragma unroll
    for (int i = 0; i < 8; ++i) {
      v4f gk = gpk0[i][(t >> i) & 1];
      acc = gk.xy * acc + gk.zw * acc.yx;
    }
    v2f l16[16];
    l16[0] = acc;
    #pragma unroll
    for (int i = 0; i < 4; ++i) {
      v4f g0 = gpk0[8 + i][0], g1 = gpk0[8 + i][1];
      #pragma unroll
      for (int j = 0; j < (1 << i); ++j) {
        v2f a = l16[j];
        l16[j | (1 << i)] = g1.xy * a + g1.zw * a.yx;
        l16[j]            = g0.xy * a + g0.zw * a.yx;
      }
    }
    #pragma unroll
    for (int j = 0; j < 16; ++j) st[tb ^ IC.ICj[j]] = f2h2(l16[j].x, l16[j].y);
  }
  __syncthreads();

  float ev[NQ];
  LDA(1, a0n, a1n)
  do_pass<0, false>(st, a0c, a1c, lane, wv, ev); __syncthreads();
  a0c = a0n; a1c = a1n; LDA(2, a0n, a1n)
  do_pass<1, false>(st, a0c, a1c, lane, wv, ev); __syncthreads();
  a0c = a0n; a1c = a1n; LDA(3, a0n, a1n)
  do_pass<2, false>(st, a0c, a1c, lane, wv, ev); __syncthreads();
  a0c = a0n; a1c = a1n; LDA(4, a0n, a1n)
  do_pass<3, false>(st, a0c, a1c, lane, wv, ev); __syncthreads();
  a0c = a0n; a1c = a1n; LDA(5, a0n, a1n)
  do_pass<4, false>(st, a0c, a1c, lane, wv, ev); __syncthreads();
  a0c = a0n; a1c = a1n;
  do_pass<5, true >(st, a0c, a1c, lane, wv, ev);  // fused readout

  // ---- reduce across lanes, then waves ----
  #pragma unroll
  for (int off = 32; off >= 1; off >>= 1) {
    #pragma unroll
    for (int i = 0; i < NQ; ++i) ev[i] += __shfl_xor(ev[i], off, 64);
  }
  if (lane == 0) {
    #pragma unroll
    for (int i = 0; i < NQ; ++i) red[wv][i] = ev[i];
  }
  __syncthreads();

  // ---- post-MLP on wave 0 via shuffles ----
  if (wv == 0 && lane < 16) {
    float q = (lane < NQ)
      ? (red[0][lane] + red[1][lane] + red[2][lane] + red[3][lane])
      : 0.f;
    float a = c1[lane];
    #pragma unroll
    for (int j = 0; j < NQ; ++j) a = fmaf(P1[lane * NQ + j], __shfl(q, j, 64), a);
    float o1 = fmaxf(a, 0.f);
    float a2 = c2[lane & 7];
    #pragma unroll
    for (int j = 0; j < 16; ++j) a2 = fmaf(P2[(lane & 7) * 16 + j], __shfl(o1, j, 64), a2);
    float o2 = fmaxf(a2, 0.f);
    float a3 = c3[0];
    #pragma unroll
    for (int j = 0; j < 8; ++j) a3 = fmaf(P3[j], __shfl(o2, j, 64), a3);
    if (lane == 0) out[s] = 1.f / (1.f + expf(-a3));
  }
}

extern "C" void kernel_launch(void* const* d_in, const int* in_sizes, int n_in,
                              void* d_out, int out_size, void* d_ws, size_t ws_size,
                              hipStream_t stream) {
  (void)in_sizes; (void)n_in; (void)ws_size;
  uint32_t* Am_g = (uint32_t*)d_ws;                       // 6*512*4 = 12288 B
  float*    U0_g = (float*)((char*)d_ws + 6 * 512 * 4);   // 12*8*4  =   384 B
  const float* qp = (const float*)d_in[7];
  prep_kernel<<<1, 256, 0, stream>>>(qp, Am_g, U0_g);
  hqc_kernel<<<out_size, TPB, 0, stream>>>(
      (const float*)d_in[0],  (const float*)d_in[1],  (const float*)d_in[2],
      (const float*)d_in[3],  (const float*)d_in[4],  (const float*)d_in[5],
      (const float*)d_in[6],
      (const float*)d_in[8],  (const float*)d_in[9],
      (const float*)d_in[10], (const float*)d_in[11],
      (const float*)d_in[12], (const float*)d_in[13],
      Am_g, U0_g,
      (float*)d_out);
}